// Round 17
// baseline (114.070 us; speedup 1.0000x reference)
//
#include <hip/hip_runtime.h>

// ---------------------------------------------------------------------------
// Devault_Single_CCNN: only the LAST timestep feeds the head -> compute only
// the causal receptive field. Every layer is a stride-2 kernel-5 conv in
// index space: Out[q] = sum_k W[k] In[2q+k], lengths 509->253->125->61->29->
// 13->5->1. bf16 MFMA 16x16x32, fp32 accumulate. THREE dispatches:
//   k_wnorm : weight-norm + MFMA-B pre-swizzle (112 blocks x 512); block 0
//             also zeroes the 64 per-batch tail counters (ws not re-zeroed
//             between graph replays -> must re-init each launch).
//   k_conv0g: gather + L0. (8qt x 64b) = 512 blocks (2/CU) x 512 thr, 44KB
//             LDS. Each block: 67 emb rows -> LDS -> 32 A0 rows global.
//   k_conv12f: L1 + L2 (r12 geometry, 256 blocks) + PIGGYBACKED TAIL: after
//             a block's L2 store, __threadfence() + atomicAdd(counter[b]);
//             the LAST of the 4 blocks per batch runs L3..L6 + head (legal
//             under undefined dispatch order: no waiting, last-arrival only;
//             device-scope atomics/fences per guide G16). Tail latency of
//             early batches overlaps conv12 work of later batches, and the
//             separate tail3 dispatch (~10-12us) disappears.
// Measured structural constants: dispatch boundary ~1-2.5us (r10); grid.sync
// ~30us (r13); >512-thr kernels VGPR-cap -> spill (r8/r10); >=2 blocks/CU for
// fused kernels (r6/r11); don't narrow a layer to save a boundary (r14);
// don't halve per-block work (B-traffic doubles, r15).
// Masking invariant: MFMA C-row m depends only on A-row m; garbage rows are
// finite and feed only outputs never read by the valid chain.
// ---------------------------------------------------------------------------

typedef __attribute__((ext_vector_type(8))) short bfrag8;   // 8 bf16
typedef __attribute__((ext_vector_type(4))) float floatx4;  // MFMA acc
typedef __attribute__((ext_vector_type(4))) short short4v;
typedef __attribute__((ext_vector_type(4))) float float4v;

__device__ __forceinline__ unsigned short f2bf(float f) {
  union { float f; unsigned u; } v; v.f = f;
  unsigned r = v.u + 0x7fffu + ((v.u >> 16) & 1u);  // RNE
  return (unsigned short)(r >> 16);
}
__device__ __forceinline__ float bf2f(unsigned short h) {
  union { unsigned u; float f; } v; v.u = ((unsigned)h) << 16;
  return v.f;
}
__device__ __forceinline__ int swz(int row) { return ((row >> 1) & 7) << 4; }

// ---------------------------------------------------------------------------
// k_wnorm: one wave per output channel; butterfly reduce; scatter swizzled WB.
// WB layout: WB[((ot*NKS + ks)*64 + lane)*8 + i], lane=(o&15)|(kg<<4),
//            kk = ks*32 + kg*8 + i, kk = tap*CPAD + c (CPAD0=320, c>=300 -> 0)
// Block 0 additionally zeroes counters[0..63] for k_conv12f's last-block
// tail (visible to the next dispatch via kernel-completion release).
// ---------------------------------------------------------------------------
__global__ __launch_bounds__(512)
void k_wnorm(const float* __restrict__ v0, const float* __restrict__ g0,
             const float* __restrict__ vr, const float* __restrict__ gr,
             unsigned short* __restrict__ WB0, unsigned short* __restrict__ WBr,
             int* __restrict__ counters) {
  if (blockIdx.x == 0 && threadIdx.x < 64) counters[threadIdx.x] = 0;
  const int gw = (blockIdx.x << 3) + (threadIdx.x >> 6);   // 0..895
  const int lane = threadIdx.x & 63;
  if (gw < 128) {                        // layer 0: K=1500 -> pad 1600
    const int o = gw;
    const float* v = v0 + o * 1500;
    float ss = 0.f;
    for (int i = lane; i < 1500; i += 64) { const float x = v[i]; ss += x * x; }
#pragma unroll
    for (int off = 32; off; off >>= 1) ss += __shfl_xor(ss, off, 64);
    const float scale = g0[o] * rsqrtf(ss);
    const int ot = o >> 4;
    for (int kk = lane; kk < 1600; kk += 64) {
      const int tap = kk / 320, c = kk % 320;
      const float w = (c < 300) ? v[c * 5 + tap] * scale : 0.f;
      const int ks = kk >> 5;
      const int li = (o & 15) | (((kk >> 3) & 3) << 4);
      WB0[(((ot * 50 + ks) * 64 + li) << 3) | (kk & 7)] = f2bf(w);
    }
  } else {                               // layers 1..6: K=640
    const int idx = gw - 128;
    const int l = idx >> 7, o = idx & 127;
    const float* v = vr + (size_t)(l * 128 + o) * 640;
    float ss = 0.f;
#pragma unroll
    for (int i = 0; i < 10; ++i) { const float x = v[lane + (i << 6)]; ss += x * x; }
#pragma unroll
    for (int off = 32; off; off >>= 1) ss += __shfl_xor(ss, off, 64);
    const float scale = gr[l * 128 + o] * rsqrtf(ss);
    unsigned short* WB = WBr + (size_t)l * 81920;
    const int ot = o >> 4;
#pragma unroll
    for (int i = 0; i < 10; ++i) {
      const int kk = lane + (i << 6);
      const int tap = kk >> 7, c = kk & 127;
      const float w = v[c * 5 + tap] * scale;
      const int ks = kk >> 5;
      const int li = (o & 15) | (((kk >> 3) & 3) << 4);
      WB[(((ot * 20 + ks) * 64 + li) << 3) | (kk & 7)] = f2bf(w);
    }
  }
}

// ---------------------------------------------------------------------------
// k_conv0g (r12 verbatim): gather + L0. Grid (8qt, 64b) x 512 thr (8 waves),
// 2 blocks/CU. Block qt: emb rows p = 64qt + [0,66] (p>=509 zeroed) ->
// embBuf pitch 656B; outputs A0 rows 32qt + [0,31]. Wave w: ot = w, 2
// m-tiles. Full 640B rows staged (no undefined bytes reach MFMA). Per-tap B
// preload = 10 frags. Garbage A0 rows >=253: finite, masked downstream.
// ---------------------------------------------------------------------------
__global__ __launch_bounds__(512, 4)
void k_conv0g(const int* __restrict__ tokens, const float* __restrict__ emb,
              const unsigned short* __restrict__ WB0, const float* __restrict__ b0,
              unsigned short* __restrict__ A0) {
  __shared__ char embBuf[67 * 656];
  __shared__ int toks[68];
  const int tid = threadIdx.x;
  const int qt = blockIdx.x, b = blockIdx.y;
  if (tid < 68) {
    const int p = (qt << 6) + tid;
    toks[tid] = (tid < 67 && p < 509) ? tokens[(b << 11) + 1539 + p] : -1;
  }
  __syncthreads();
  for (int idx = tid; idx < 67 * 80; idx += 512) {
    const int r = idx / 80, s = idx - r * 80;
    short4v o = {0, 0, 0, 0};
    const int tok = toks[r];
    if (tok >= 0 && s < 75) {
      const float4v v = *(const float4v*)(emb + (size_t)tok * 300 + (s << 2));
      o[0] = (short)f2bf(v[0]); o[1] = (short)f2bf(v[1]);
      o[2] = (short)f2bf(v[2]); o[3] = (short)f2bf(v[3]);
    }
    *(short4v*)(embBuf + r * 656 + (s << 3)) = o;
  }
  __syncthreads();
  const int lane = tid & 63, w = tid >> 6;      // ot = w
  const int qb = lane & 15, kg = lane >> 4;
  floatx4 acc[2];
  acc[0] = floatx4{0.f, 0.f, 0.f, 0.f};
  acc[1] = floatx4{0.f, 0.f, 0.f, 0.f};
  const unsigned short* wb0 = WB0 + (size_t)(((w * 50) << 6) + lane) * 8;
#pragma unroll
  for (int tap = 0; tap < 5; ++tap) {
    bfrag8 bf[10];
#pragma unroll
    for (int cs = 0; cs < 10; ++cs)
      bf[cs] = *(const bfrag8*)(wb0 + ((tap * 10 + cs) << 9));
#pragma unroll
    for (int cs = 0; cs < 10; ++cs) {
      const int cb = (cs << 6) + (kg << 4);
#pragma unroll
      for (int m = 0; m < 2; ++m) {
        const int row = (((m << 4) + qb) << 1) + tap;        // <= 66
        const bfrag8 a = *(const bfrag8*)(embBuf + row * 656 + cb);
        acc[m] = __builtin_amdgcn_mfma_f32_16x16x32_bf16(a, bf[cs], acc[m], 0, 0, 0);
      }
    }
  }
  unsigned short* ob = A0 + (((size_t)b << 8) + (qt << 5)) * 128;
  const int o = (w << 4) + qb;
  const float bv = b0[o];
#pragma unroll
  for (int m = 0; m < 2; ++m)
#pragma unroll
    for (int r = 0; r < 4; ++r) {
      const int ql = (m << 4) + (kg << 2) + r;               // 0..31
      ob[ql * 128 + o] = f2bf(fmaxf(acc[m][r] + bv, 0.f));
    }
}

// ---------------------------------------------------------------------------
// conv_l (proven r12): K=640 layer, NMTW m-tiles at mt0 x NOTW ot's at
// og*NOTW. B per-tap preload (<=8 frags = 32 VGPR). A from swizzled
// 256B-pitch LDS. Stores masked to qq < MCAP (inside destination alloc).
// ---------------------------------------------------------------------------
template<int NMTW, int NOTW, int MCAP>
__device__ __forceinline__ void conv_l(const char* bi, char* bo,
    const unsigned short* __restrict__ WBl, const float* __restrict__ bias,
    int mt0, int og, int qb, int kg, int lane) {
  floatx4 acc[NMTW][NOTW];
#pragma unroll
  for (int m = 0; m < NMTW; ++m)
#pragma unroll
    for (int j = 0; j < NOTW; ++j) acc[m][j] = floatx4{0.f, 0.f, 0.f, 0.f};
#pragma unroll
  for (int tap = 0; tap < 5; ++tap) {
    bfrag8 bfs[NOTW][4];
#pragma unroll
    for (int j = 0; j < NOTW; ++j)
#pragma unroll
      for (int cs = 0; cs < 4; ++cs)
        bfs[j][cs] = *(const bfrag8*)(WBl +
            (size_t)((((og * NOTW + j) * 20 + (tap << 2) + cs) << 6) + lane) * 8);
#pragma unroll
    for (int cs = 0; cs < 4; ++cs) {
      const int cb = (cs << 6) + (kg << 4);
#pragma unroll
      for (int m = 0; m < NMTW; ++m) {
        const int row = (((mt0 + m) << 4) + qb) * 2 + tap;
        const bfrag8 a = *(const bfrag8*)(bi + (((row << 8) + cb) ^ swz(row)));
#pragma unroll
        for (int j = 0; j < NOTW; ++j)
          acc[m][j] = __builtin_amdgcn_mfma_f32_16x16x32_bf16(a, bfs[j][cs], acc[m][j], 0, 0, 0);
      }
    }
  }
#pragma unroll
  for (int m = 0; m < NMTW; ++m)
#pragma unroll
    for (int j = 0; j < NOTW; ++j) {
      const int o = ((og * NOTW + j) << 4) + qb;
      const float bv = bias[o];
#pragma unroll
      for (int r = 0; r < 4; ++r) {
        const int qq = ((mt0 + m) << 4) + (kg << 2) + r;
        if (qq < MCAP)
          *(unsigned short*)(bo + (((qq << 8) + (o << 1)) ^ swz(qq))) =
              f2bf(fmaxf(acc[m][j][r] + bv, 0.f));
      }
    }
}

// ---------------------------------------------------------------------------
// k_conv12f: L1 + L2 (r12 geometry verbatim) + last-block tail.
// Grid (4 qt, 64 b) x 512 thr. LDS arena reused: conv phase a0stage(25.6K)+
// l1buf(9.2K)=34.8K; tail phase bufS(17.4K)+bufT(9.2K)+h(384)=27K.
// After L2 store: __threadfence (release) + atomicAdd(counter[b]); the 4th
// arriver re-fences (acquire) and runs L3..L6 + head for batch b. No block
// ever waits -> safe under undefined dispatch order. Output deterministic
// (tail reads fully-written L2out regardless of which block runs it).
// Tail garbage audit = r12 tail3: bufS staged 61 rows, masked reads <=66 hit
// stale-but-finite arena bytes (f2bf outputs/zeros); bufT masked reads <=34;
// all garbage feeds only masked C-rows (MFMA row isolation).
// ---------------------------------------------------------------------------
__global__ __launch_bounds__(512, 1)
void k_conv12f(const unsigned short* __restrict__ A0,
               const unsigned short* __restrict__ WBr, const float* __restrict__ br,
               unsigned short* __restrict__ L2out, int* __restrict__ counters,
               const float* __restrict__ de,
               const float* __restrict__ w1, const float* __restrict__ b1,
               const float* __restrict__ w2, const float* __restrict__ b2,
               const float* __restrict__ w3, const float* __restrict__ b3,
               float* __restrict__ out) {
  __shared__ char arena[34816];
  __shared__ int isLast;
  char* a0stage = arena;                 // 100 x 256
  char* l1buf   = arena + 25600;         // 36 x 256
  const int tid = threadIdx.x;
  const int qt = blockIdx.x, b = blockIdx.y;
  const char* a0b = (const char*)(A0 + ((size_t)b << 15));
  for (int idx = tid; idx < 100 * 16; idx += 512) {
    const int r = idx >> 4, s = idx & 15;
    float4v v = {0.f, 0.f, 0.f, 0.f};
    if (r < 73) {
      int rs = (qt << 6) + r; if (rs > 255) rs = 255;
      v = *(const float4v*)(a0b + (rs << 8) + (s << 4));
    }
    *(float4v*)(a0stage + (((r << 8) + (s << 4)) ^ swz(r))) = v;
  }
  __syncthreads();
  const int lane = tid & 63, w = tid >> 6;
  const int og = w & 3, mgh = w >> 2;
  const int qb = lane & 15, kg = lane >> 4;
  if (mgh == 0) conv_l<2, 2, 36>(a0stage, l1buf, WBr, br, 0, og, qb, kg, lane);
  else          conv_l<1, 2, 36>(a0stage, l1buf, WBr, br, 2, og, qb, kg, lane);
  __syncthreads();
  {                                      // L2 -> global (q2 = 16qt+local < 61)
    floatx4 acc = {0.f, 0.f, 0.f, 0.f};
    const unsigned short* wbl = WBr + 81920;
#pragma unroll
    for (int tap = 0; tap < 5; ++tap) {
      bfrag8 bfs[4];
#pragma unroll
      for (int cs = 0; cs < 4; ++cs)
        bfs[cs] = *(const bfrag8*)(wbl +
            (size_t)(((w * 20 + (tap << 2) + cs) << 6) + lane) * 8);
#pragma unroll
      for (int cs = 0; cs < 4; ++cs) {
        const int cb = (cs << 6) + (kg << 4);
        const int row = (qb << 1) + tap;                     // <= 34 < 36
        const bfrag8 a = *(const bfrag8*)(l1buf + (((row << 8) + cb) ^ swz(row)));
        acc = __builtin_amdgcn_mfma_f32_16x16x32_bf16(a, bfs[cs], acc, 0, 0, 0);
      }
    }
    const int o = (w << 4) + qb;
    const float bv = br[128 + o];
    unsigned short* ob = L2out + ((size_t)b << 13);          // 64 rows x 128
#pragma unroll
    for (int r = 0; r < 4; ++r) {
      const int q2 = (qt << 4) + (kg << 2) + r;
      if (q2 < 61) ob[(q2 << 7) + o] = f2bf(fmaxf(acc[r] + bv, 0.f));
    }
  }
  // ---- last-arriving block of batch b runs the tail ----
  __threadfence();                       // release our L2out stores
  if (tid == 0) isLast = (atomicAdd(&counters[b], 1) == 3);
  __syncthreads();
  if (!isLast) return;
  __threadfence();                       // acquire other blocks' L2out stores

  char* bufS = arena;                    // 68 x 256 = 17408
  char* bufT = arena + 17408;            // 36 x 256
  float* h1 = (float*)(arena + 26624);
  float* h2 = h1 + 64;
  const char* l2b = (const char*)(L2out + ((size_t)b << 13));
  for (int idx = tid; idx < 61 * 16; idx += 512) {
    const int r = idx >> 4, s = idx & 15;
    *(float4v*)(bufS + (((r << 8) + (s << 4)) ^ swz(r))) =
        *(const float4v*)(l2b + (r << 8) + (s << 4));
  }
  __syncthreads();

  conv_l<1, 2, 32>(bufS, bufT, WBr + 2 * 81920, br + 256, w & 1, w >> 1, qb, kg, lane); // L3 M=29
  __syncthreads();
  conv_l<1, 1, 16>(bufT, bufS, WBr + 3 * 81920, br + 384, 0, w, qb, kg, lane);          // L4 M=13
  __syncthreads();
  conv_l<1, 1, 16>(bufS, bufT, WBr + 4 * 81920, br + 512, 0, w, qb, kg, lane);          // L5 M=5
  __syncthreads();
  conv_l<1, 1, 16>(bufT, bufS, WBr + 5 * 81920, br + 640, 0, w, qb, kg, lane);          // L6 M=1
  __syncthreads();

  // head: combo = [bufS row 0 (swz identity), de] -> 64 -> 32 -> 1
  const unsigned short* o6 = (const unsigned short*)bufS;
  {                                      // h1: 64 outs x 8 threads
    const int o1 = tid >> 3, part = tid & 7;
    const int j0 = part * 18;
    const int j1 = (j0 + 18 < 139) ? j0 + 18 : 139;
    float s = 0.f;
    const float* wrow = w1 + o1 * 139;
    for (int j = j0; j < j1; ++j) {
      const float x = (j < 128) ? bf2f(o6[j]) : de[b * 11 + (j - 128)];
      s += wrow[j] * x;
    }
    s += __shfl_down(s, 4, 64);
    s += __shfl_down(s, 2, 64);
    s += __shfl_down(s, 1, 64);
    if (part == 0) h1[o1] = fmaxf(s + b1[o1], 0.f);
  }
  __syncthreads();
  if (tid < 64) {                        // h2: 32 outs x 2 threads
    const int o2 = tid >> 1, part = tid & 1;
    float s = 0.f;
    const float* wrow = w2 + o2 * 64 + part * 32;
    for (int j = 0; j < 32; ++j) s += wrow[j] * h1[part * 32 + j];
    s += __shfl_down(s, 1, 64);
    if (part == 0) h2[o2] = fmaxf(s + b2[o2], 0.f);
  }
  __syncthreads();
  if (tid < 32) {
    float s = w3[tid] * h2[tid];
    s += __shfl_down(s, 16, 64);
    s += __shfl_down(s, 8, 64);
    s += __shfl_down(s, 4, 64);
    s += __shfl_down(s, 2, 64);
    s += __shfl_down(s, 1, 64);
    if (tid == 0) out[b] = s + b3[0];
  }
}

// ---------------------------------------------------------------------------
extern "C" void kernel_launch(void* const* d_in, const int* in_sizes, int n_in,
                              void* d_out, int out_size, void* d_ws, size_t ws_size,
                              hipStream_t stream) {
  const int*   tokens = (const int*)  d_in[0];
  const float* de     = (const float*)d_in[1];
  const float* emb    = (const float*)d_in[2];
  const float* v0     = (const float*)d_in[3];
  const float* g0     = (const float*)d_in[4];
  const float* b0     = (const float*)d_in[5];
  const float* vr     = (const float*)d_in[6];
  const float* gr     = (const float*)d_in[7];
  const float* br     = (const float*)d_in[8];
  const float* w1     = (const float*)d_in[9];
  const float* b1     = (const float*)d_in[10];
  const float* w2     = (const float*)d_in[11];
  const float* b2     = (const float*)d_in[12];
  const float* w3     = (const float*)d_in[13];
  const float* b3     = (const float*)d_in[14];
  float* out = (float*)d_out;

  char* w = (char*)d_ws;
  unsigned short* WB0   = (unsigned short*)(w + 0);        // 128x1600 bf16
  unsigned short* WBr   = (unsigned short*)(w + 409600);   // 6 x 128x640 bf16
  unsigned short* A0    = (unsigned short*)(w + 1392640);  // [64][256][128] bf16
  unsigned short* L2out = (unsigned short*)(w + 5586944);  // [64][64][128] bf16
  int* counters         = (int*)(w + 6635520);             // [64]

  hipLaunchKernelGGL(k_wnorm, dim3(112), dim3(512), 0, stream,
                     v0, g0, vr, gr, WB0, WBr, counters);
  hipLaunchKernelGGL(k_conv0g, dim3(8, 64), dim3(512), 0, stream,
                     tokens, emb, WB0, b0, A0);
  hipLaunchKernelGGL(k_conv12f, dim3(4, 64), dim3(512), 0, stream,
                     A0, WBr, br, L2out, counters,
                     de, w1, b1, w2, b2, w3, b3, out);
}

// Round 18
// 65.773 us; speedup vs baseline: 1.7343x; 1.7343x over previous
//
#include <hip/hip_runtime.h>

// ---------------------------------------------------------------------------
// Devault_Single_CCNN: only the LAST timestep feeds the head -> compute only
// the causal receptive field. Every layer is a stride-2 kernel-5 conv in
// index space: Out[q] = sum_k W[k] In[2q+k], lengths 509->253->125->61->29->
// 13->5->1. bf16 MFMA 16x16x32, fp32 accumulate. FOUR dispatches — the
// champion structure (r12 = 66.1us, r16 = 65.8us), restored after r17's
// piggyback-tail experiment (VGPR clamp to 64 in the merged kernel -> 114us).
//   k_wnorm : weight-norm + MFMA-B pre-swizzle (112 blocks x 512).
//   k_conv0g: gather + L0. (8qt x 64b) = 512 blocks (2/CU) x 512 thr, 44KB
//             LDS. Each block: 67 emb rows -> LDS -> 32 A0 rows global.
//   k_conv12: L1 + L2 fused. (4qt x 64b) = 256 blocks x 512 thr.
//   k_tail3 : L3..L6 + FC head. 64 blocks x 512 thr, 27KB LDS.
// Measured structural constants from this session:
//   dispatch boundary ~1-2.5us (r10); grid.sync ~30us (r13); >512-thr or
//   path-union kernels VGPR-cap -> spill/serialize (r8/r10/r17); fused
//   kernels need >=2 blocks/CU (r6/r11); narrowing a layer to save a
//   boundary loses (r14); halving per-block work doubles B-traffic (r15).
// Plateau: 12 structures bracket 66-131us; serial 8-layer chain of tiny
// per-layer work => latency-bound, not HBM/MFMA-bound.
// Masking invariant: MFMA C-row m depends only on A-row m; garbage rows are
// finite and feed only outputs never read by the valid chain.
// ---------------------------------------------------------------------------

typedef __attribute__((ext_vector_type(8))) short bfrag8;   // 8 bf16
typedef __attribute__((ext_vector_type(4))) float floatx4;  // MFMA acc
typedef __attribute__((ext_vector_type(4))) short short4v;
typedef __attribute__((ext_vector_type(4))) float float4v;

__device__ __forceinline__ unsigned short f2bf(float f) {
  union { float f; unsigned u; } v; v.f = f;
  unsigned r = v.u + 0x7fffu + ((v.u >> 16) & 1u);  // RNE
  return (unsigned short)(r >> 16);
}
__device__ __forceinline__ float bf2f(unsigned short h) {
  union { unsigned u; float f; } v; v.u = ((unsigned)h) << 16;
  return v.f;
}
__device__ __forceinline__ int swz(int row) { return ((row >> 1) & 7) << 4; }

// ---------------------------------------------------------------------------
// k_wnorm: one wave per output channel; butterfly reduce; scatter swizzled WB.
// WB layout: WB[((ot*NKS + ks)*64 + lane)*8 + i], lane=(o&15)|(kg<<4),
//            kk = ks*32 + kg*8 + i, kk = tap*CPAD + c (CPAD0=320, c>=300 -> 0)
// ---------------------------------------------------------------------------
__global__ __launch_bounds__(512)
void k_wnorm(const float* __restrict__ v0, const float* __restrict__ g0,
             const float* __restrict__ vr, const float* __restrict__ gr,
             unsigned short* __restrict__ WB0, unsigned short* __restrict__ WBr) {
  const int gw = (blockIdx.x << 3) + (threadIdx.x >> 6);   // 0..895
  const int lane = threadIdx.x & 63;
  if (gw < 128) {                        // layer 0: K=1500 -> pad 1600
    const int o = gw;
    const float* v = v0 + o * 1500;
    float ss = 0.f;
    for (int i = lane; i < 1500; i += 64) { const float x = v[i]; ss += x * x; }
#pragma unroll
    for (int off = 32; off; off >>= 1) ss += __shfl_xor(ss, off, 64);
    const float scale = g0[o] * rsqrtf(ss);
    const int ot = o >> 4;
    for (int kk = lane; kk < 1600; kk += 64) {
      const int tap = kk / 320, c = kk % 320;
      const float w = (c < 300) ? v[c * 5 + tap] * scale : 0.f;
      const int ks = kk >> 5;
      const int li = (o & 15) | (((kk >> 3) & 3) << 4);
      WB0[(((ot * 50 + ks) * 64 + li) << 3) | (kk & 7)] = f2bf(w);
    }
  } else {                               // layers 1..6: K=640
    const int idx = gw - 128;
    const int l = idx >> 7, o = idx & 127;
    const float* v = vr + (size_t)(l * 128 + o) * 640;
    float ss = 0.f;
#pragma unroll
    for (int i = 0; i < 10; ++i) { const float x = v[lane + (i << 6)]; ss += x * x; }
#pragma unroll
    for (int off = 32; off; off >>= 1) ss += __shfl_xor(ss, off, 64);
    const float scale = gr[l * 128 + o] * rsqrtf(ss);
    unsigned short* WB = WBr + (size_t)l * 81920;
    const int ot = o >> 4;
#pragma unroll
    for (int i = 0; i < 10; ++i) {
      const int kk = lane + (i << 6);
      const int tap = kk >> 7, c = kk & 127;
      const float w = v[c * 5 + tap] * scale;
      const int ks = kk >> 5;
      const int li = (o & 15) | (((kk >> 3) & 3) << 4);
      WB[(((ot * 20 + ks) * 64 + li) << 3) | (kk & 7)] = f2bf(w);
    }
  }
}

// ---------------------------------------------------------------------------
// k_conv0g: gather + L0. Grid (8 qt, 64 b) x 512 thr (8 waves), 2 blocks/CU.
// Block qt: emb rows p = 64qt + [0,66] (p>=509 zeroed) -> embBuf pitch 656B;
// outputs A0 rows 32qt + [0,31]. Wave w: ot = w, 2 m-tiles.
// Full 640B rows staged (no undefined bytes reach MFMA). Per-tap B preload
// = 10 frags (40 VGPR, bounded). Garbage A0 rows >=253: convolved zeros +
// bias = finite, masked downstream.
// ---------------------------------------------------------------------------
__global__ __launch_bounds__(512, 4)
void k_conv0g(const int* __restrict__ tokens, const float* __restrict__ emb,
              const unsigned short* __restrict__ WB0, const float* __restrict__ b0,
              unsigned short* __restrict__ A0) {
  __shared__ char embBuf[67 * 656];
  __shared__ int toks[68];
  const int tid = threadIdx.x;
  const int qt = blockIdx.x, b = blockIdx.y;
  if (tid < 68) {
    const int p = (qt << 6) + tid;
    toks[tid] = (tid < 67 && p < 509) ? tokens[(b << 11) + 1539 + p] : -1;
  }
  __syncthreads();
  // gather 67 rows x 640B (full rows: no undefined bytes reach MFMA)
  for (int idx = tid; idx < 67 * 80; idx += 512) {
    const int r = idx / 80, s = idx - r * 80;
    short4v o = {0, 0, 0, 0};
    const int tok = toks[r];
    if (tok >= 0 && s < 75) {
      const float4v v = *(const float4v*)(emb + (size_t)tok * 300 + (s << 2));
      o[0] = (short)f2bf(v[0]); o[1] = (short)f2bf(v[1]);
      o[2] = (short)f2bf(v[2]); o[3] = (short)f2bf(v[3]);
    }
    *(short4v*)(embBuf + r * 656 + (s << 3)) = o;
  }
  __syncthreads();
  const int lane = tid & 63, w = tid >> 6;      // ot = w
  const int qb = lane & 15, kg = lane >> 4;
  floatx4 acc[2];
  acc[0] = floatx4{0.f, 0.f, 0.f, 0.f};
  acc[1] = floatx4{0.f, 0.f, 0.f, 0.f};
  const unsigned short* wb0 = WB0 + (size_t)(((w * 50) << 6) + lane) * 8;
#pragma unroll
  for (int tap = 0; tap < 5; ++tap) {
    bfrag8 bf[10];
#pragma unroll
    for (int cs = 0; cs < 10; ++cs)
      bf[cs] = *(const bfrag8*)(wb0 + ((tap * 10 + cs) << 9));
#pragma unroll
    for (int cs = 0; cs < 10; ++cs) {
      const int cb = (cs << 6) + (kg << 4);
#pragma unroll
      for (int m = 0; m < 2; ++m) {
        const int row = (((m << 4) + qb) << 1) + tap;        // <= 66
        const bfrag8 a = *(const bfrag8*)(embBuf + row * 656 + cb);
        acc[m] = __builtin_amdgcn_mfma_f32_16x16x32_bf16(a, bf[cs], acc[m], 0, 0, 0);
      }
    }
  }
  unsigned short* ob = A0 + (((size_t)b << 8) + (qt << 5)) * 128;
  const int o = (w << 4) + qb;
  const float bv = b0[o];
#pragma unroll
  for (int m = 0; m < 2; ++m)
#pragma unroll
    for (int r = 0; r < 4; ++r) {
      const int ql = (m << 4) + (kg << 2) + r;               // 0..31
      ob[ql * 128 + o] = f2bf(fmaxf(acc[m][r] + bv, 0.f));
    }
}

// ---------------------------------------------------------------------------
// conv_l (proven r12): K=640 layer, NMTW m-tiles at mt0 x NOTW ot's at
// og*NOTW. B per-tap preload (<=8 frags = 32 VGPR). A from swizzled
// 256B-pitch LDS. Stores masked to qq < MCAP (inside destination alloc).
// ---------------------------------------------------------------------------
template<int NMTW, int NOTW, int MCAP>
__device__ __forceinline__ void conv_l(const char* bi, char* bo,
    const unsigned short* __restrict__ WBl, const float* __restrict__ bias,
    int mt0, int og, int qb, int kg, int lane) {
  floatx4 acc[NMTW][NOTW];
#pragma unroll
  for (int m = 0; m < NMTW; ++m)
#pragma unroll
    for (int j = 0; j < NOTW; ++j) acc[m][j] = floatx4{0.f, 0.f, 0.f, 0.f};
#pragma unroll
  for (int tap = 0; tap < 5; ++tap) {
    bfrag8 bfs[NOTW][4];
#pragma unroll
    for (int j = 0; j < NOTW; ++j)
#pragma unroll
      for (int cs = 0; cs < 4; ++cs)
        bfs[j][cs] = *(const bfrag8*)(WBl +
            (size_t)((((og * NOTW + j) * 20 + (tap << 2) + cs) << 6) + lane) * 8);
#pragma unroll
    for (int cs = 0; cs < 4; ++cs) {
      const int cb = (cs << 6) + (kg << 4);
#pragma unroll
      for (int m = 0; m < NMTW; ++m) {
        const int row = (((mt0 + m) << 4) + qb) * 2 + tap;
        const bfrag8 a = *(const bfrag8*)(bi + (((row << 8) + cb) ^ swz(row)));
#pragma unroll
        for (int j = 0; j < NOTW; ++j)
          acc[m][j] = __builtin_amdgcn_mfma_f32_16x16x32_bf16(a, bfs[j][cs], acc[m][j], 0, 0, 0);
      }
    }
  }
#pragma unroll
  for (int m = 0; m < NMTW; ++m)
#pragma unroll
    for (int j = 0; j < NOTW; ++j) {
      const int o = ((og * NOTW + j) << 4) + qb;
      const float bv = bias[o];
#pragma unroll
      for (int r = 0; r < 4; ++r) {
        const int qq = ((mt0 + m) << 4) + (kg << 2) + r;
        if (qq < MCAP)
          *(unsigned short*)(bo + (((qq << 8) + (o << 1)) ^ swz(qq))) =
              f2bf(fmaxf(acc[m][j][r] + bv, 0.f));
      }
    }
}

// ---------------------------------------------------------------------------
// k_conv12 (r12 verbatim): L1 + L2. Grid (4 qt, 64 b) x 512 thr.
// Stage A0 rows [64qt..64qt+72] (clamp <=255) -> a0stage rows 0..72; rows
// 73..99 zeroed. L1: 3 m-tiles -> l1buf rows 0..35 (valid r1<=34; L2's valid
// outputs read only r1<=34 which read staged A0 rows <=72). L2: all 8 waves
// (ot=w), global store q2<61.
// ---------------------------------------------------------------------------
__global__ __launch_bounds__(512, 1)
void k_conv12(const unsigned short* __restrict__ A0,
              const unsigned short* __restrict__ WBr, const float* __restrict__ br,
              unsigned short* __restrict__ L2out) {
  __shared__ char a0stage[100 * 256];
  __shared__ char l1buf[36 * 256];
  const int tid = threadIdx.x;
  const int qt = blockIdx.x, b = blockIdx.y;
  const char* a0b = (const char*)(A0 + ((size_t)b << 15));
  for (int idx = tid; idx < 100 * 16; idx += 512) {
    const int r = idx >> 4, s = idx & 15;
    float4v v = {0.f, 0.f, 0.f, 0.f};
    if (r < 73) {
      int rs = (qt << 6) + r; if (rs > 255) rs = 255;
      v = *(const float4v*)(a0b + (rs << 8) + (s << 4));
    }
    *(float4v*)(a0stage + (((r << 8) + (s << 4)) ^ swz(r))) = v;
  }
  __syncthreads();
  const int lane = tid & 63, w = tid >> 6;
  const int og = w & 3, mgh = w >> 2;
  const int qb = lane & 15, kg = lane >> 4;
  if (mgh == 0) conv_l<2, 2, 36>(a0stage, l1buf, WBr, br, 0, og, qb, kg, lane);
  else          conv_l<1, 2, 36>(a0stage, l1buf, WBr, br, 2, og, qb, kg, lane);
  __syncthreads();
  {
    floatx4 acc = {0.f, 0.f, 0.f, 0.f};
    const unsigned short* wbl = WBr + 81920;
#pragma unroll
    for (int tap = 0; tap < 5; ++tap) {
      bfrag8 bfs[4];
#pragma unroll
      for (int cs = 0; cs < 4; ++cs)
        bfs[cs] = *(const bfrag8*)(wbl +
            (size_t)(((w * 20 + (tap << 2) + cs) << 6) + lane) * 8);
#pragma unroll
      for (int cs = 0; cs < 4; ++cs) {
        const int cb = (cs << 6) + (kg << 4);
        const int row = (qb << 1) + tap;                     // <= 34 < 36
        const bfrag8 a = *(const bfrag8*)(l1buf + (((row << 8) + cb) ^ swz(row)));
        acc = __builtin_amdgcn_mfma_f32_16x16x32_bf16(a, bfs[cs], acc, 0, 0, 0);
      }
    }
    const int o = (w << 4) + qb;
    const float bv = br[128 + o];
    unsigned short* ob = L2out + ((size_t)b << 13);          // 64 rows x 128
#pragma unroll
    for (int r = 0; r < 4; ++r) {
      const int q2 = (qt << 4) + (kg << 2) + r;
      if (q2 < 61) ob[(q2 << 7) + o] = f2bf(fmaxf(acc[r] + bv, 0.f));
    }
  }
}

// ---------------------------------------------------------------------------
// k_tail3 (r12 verbatim): L3..L6 + head. 64 blocks x 512 thr. LDS 27KB.
// bufS 68 rows (stage 61; masked reads <=66); bufT 36 rows (masked <=34).
// S->T(L3)->S(L4)->T(L5)->S(L6); head reads S row 0 (swz identity).
// ---------------------------------------------------------------------------
__global__ __launch_bounds__(512, 1)
void k_tail3(const unsigned short* __restrict__ L2out, const unsigned short* __restrict__ WBr,
             const float* __restrict__ br, const float* __restrict__ de,
             const float* __restrict__ w1, const float* __restrict__ b1,
             const float* __restrict__ w2, const float* __restrict__ b2,
             const float* __restrict__ w3, const float* __restrict__ b3,
             float* __restrict__ out) {
  __shared__ char lds2[68 * 256 + 36 * 256 + 384];
  char* bufS = lds2;
  char* bufT = lds2 + 68 * 256;
  float* h1 = (float*)(lds2 + 68 * 256 + 36 * 256);
  float* h2 = h1 + 64;
  const int tid = threadIdx.x, b = blockIdx.x;
  const int lane = tid & 63, w = tid >> 6;
  const int qb = lane & 15, kg = lane >> 4;

  const char* l2b = (const char*)(L2out + ((size_t)b << 13));
  for (int idx = tid; idx < 61 * 16; idx += 512) {
    const int r = idx >> 4, s = idx & 15;
    *(float4v*)(bufS + (((r << 8) + (s << 4)) ^ swz(r))) =
        *(const float4v*)(l2b + (r << 8) + (s << 4));
  }
  __syncthreads();

  conv_l<1, 2, 32>(bufS, bufT, WBr + 2 * 81920, br + 256, w & 1, w >> 1, qb, kg, lane); // L3 M=29
  __syncthreads();
  conv_l<1, 1, 16>(bufT, bufS, WBr + 3 * 81920, br + 384, 0, w, qb, kg, lane);          // L4 M=13
  __syncthreads();
  conv_l<1, 1, 16>(bufS, bufT, WBr + 4 * 81920, br + 512, 0, w, qb, kg, lane);          // L5 M=5
  __syncthreads();
  conv_l<1, 1, 16>(bufT, bufS, WBr + 5 * 81920, br + 640, 0, w, qb, kg, lane);          // L6 M=1
  __syncthreads();

  const unsigned short* o6 = (const unsigned short*)bufS;
  {                                      // h1: 64 outs x 8 threads
    const int o1 = tid >> 3, part = tid & 7;
    const int j0 = part * 18;
    const int j1 = (j0 + 18 < 139) ? j0 + 18 : 139;
    float s = 0.f;
    const float* wrow = w1 + o1 * 139;
    for (int j = j0; j < j1; ++j) {
      const float x = (j < 128) ? bf2f(o6[j]) : de[b * 11 + (j - 128)];
      s += wrow[j] * x;
    }
    s += __shfl_down(s, 4, 64);
    s += __shfl_down(s, 2, 64);
    s += __shfl_down(s, 1, 64);
    if (part == 0) h1[o1] = fmaxf(s + b1[o1], 0.f);
  }
  __syncthreads();
  if (tid < 64) {                        // h2: 32 outs x 2 threads
    const int o2 = tid >> 1, part = tid & 1;
    float s = 0.f;
    const float* wrow = w2 + o2 * 64 + part * 32;
    for (int j = 0; j < 32; ++j) s += wrow[j] * h1[part * 32 + j];
    s += __shfl_down(s, 1, 64);
    if (part == 0) h2[o2] = fmaxf(s + b2[o2], 0.f);
  }
  __syncthreads();
  if (tid < 32) {
    float s = w3[tid] * h2[tid];
    s += __shfl_down(s, 16, 64);
    s += __shfl_down(s, 8, 64);
    s += __shfl_down(s, 4, 64);
    s += __shfl_down(s, 2, 64);
    s += __shfl_down(s, 1, 64);
    if (tid == 0) out[b] = s + b3[0];
  }
}

// ---------------------------------------------------------------------------
extern "C" void kernel_launch(void* const* d_in, const int* in_sizes, int n_in,
                              void* d_out, int out_size, void* d_ws, size_t ws_size,
                              hipStream_t stream) {
  const int*   tokens = (const int*)  d_in[0];
  const float* de     = (const float*)d_in[1];
  const float* emb    = (const float*)d_in[2];
  const float* v0     = (const float*)d_in[3];
  const float* g0     = (const float*)d_in[4];
  const float* b0     = (const float*)d_in[5];
  const float* vr     = (const float*)d_in[6];
  const float* gr     = (const float*)d_in[7];
  const float* br     = (const float*)d_in[8];
  const float* w1     = (const float*)d_in[9];
  const float* b1     = (const float*)d_in[10];
  const float* w2     = (const float*)d_in[11];
  const float* b2     = (const float*)d_in[12];
  const float* w3     = (const float*)d_in[13];
  const float* b3     = (const float*)d_in[14];
  float* out = (float*)d_out;

  char* w = (char*)d_ws;
  unsigned short* WB0   = (unsigned short*)(w + 0);        // 128x1600 bf16
  unsigned short* WBr   = (unsigned short*)(w + 409600);   // 6 x 128x640 bf16
  unsigned short* A0    = (unsigned short*)(w + 1392640);  // [64][256][128] bf16
  unsigned short* L2out = (unsigned short*)(w + 5586944);  // [64][64][128] bf16

  hipLaunchKernelGGL(k_wnorm, dim3(112), dim3(512), 0, stream, v0, g0, vr, gr, WB0, WBr);
  hipLaunchKernelGGL(k_conv0g, dim3(8, 64), dim3(512), 0, stream,
                     tokens, emb, WB0, b0, A0);
  hipLaunchKernelGGL(k_conv12, dim3(4, 64), dim3(512), 0, stream, A0, WBr, br, L2out);
  hipLaunchKernelGGL(k_tail3, dim3(64), dim3(512), 0, stream,
                     L2out, WBr, br, de, w1, b1, w2, b2, w3, b3, out);
}